// Round 12
// baseline (60.685 us; speedup 1.0000x reference)
//
#include <hip/hip_runtime.h>
#include <hip/hip_bf16.h>
#include <math.h>

#define HH 768
#define NB 8
#define LL 256
#define MM 128
#define NROW1 (NB*MM)        // 1024 dns rows
#define NROW2 (NB*LL)        // 2048 text rows
#define NROWS (NROW1+NROW2)  // 3072
#define NCB 12               // 768/64 column blocks

typedef __attribute__((ext_vector_type(8))) short  bf16x8;
typedef __attribute__((ext_vector_type(4))) float  f32x4;

static __device__ __forceinline__ unsigned int pkbf2(float a, float b) {
    __hip_bfloat162 h = __float22bfloat162_rn(make_float2(a, b));
    unsigned int u; __builtin_memcpy(&u, &h, 4); return u;
}

static __device__ __forceinline__ float fast_tanh(float x) {
    float e = __expf(2.0f * x);
    return 1.0f - 2.0f * __builtin_amdgcn_rcpf(e + 1.0f);
}

// ---------------------------------------------------------------------------
// One-shot fp32 -> bf16 conversion of all GEMM operands. (verbatim r4-r7)
// ---------------------------------------------------------------------------
__global__ __launch_bounds__(256) void prep_bf16(
    const float4* __restrict__ text, const float4* __restrict__ dns,
    const float4* __restrict__ Wd1, const float4* __restrict__ Wt2,
    uint2* __restrict__ Xb, uint2* __restrict__ Wb)
{
    const int i = blockIdx.x * 256 + threadIdx.x;   // 884736 threads exactly
    const float4* src; uint2* dst;
    if (i < 589824) {
        dst = Xb + i;
        src = (i < 196608) ? (dns + i) : (text + (i - 196608));
    } else {
        dst = Wb + (i - 589824);
        src = (i < 737280) ? (Wd1 + (i - 589824)) : (Wt2 + (i - 737280));
    }
    float4 v = *src;
    uint2 o; o.x = pkbf2(v.x, v.y); o.y = pkbf2(v.z, v.w);
    *dst = o;
}

// ---------------------------------------------------------------------------
// Score GEMM v6: LDS-free, BARRIER-free. Both A and B fragments are direct
// per-lane uint4 global loads (addresses identical to what the proven LDS
// versions staged: row|col = lc, k = lk + 32*s -> bit-identical numerics).
// Per 32-k step: 5 loads + 4 MFMAs; 24 steps; 3-deep register pipeline.
// No lockstep: waves drift freely, 9 waves/CU with 5 outstanding loads each
// hide L2 latency; the block's 4 waves share B lines via L1 (traffic ~= r7).
// Grid 576, XCD-chunked bijective swizzle, epilogue verbatim r7.
// ---------------------------------------------------------------------------
__global__ __launch_bounds__(256) void score_mfma(
    const unsigned short* __restrict__ Xb, const unsigned short* __restrict__ Wb,
    const float* __restrict__ wv1, const float* __restrict__ wv2,
    float* __restrict__ partial)
{
    const int t = threadIdx.x;
    const int tile = (blockIdx.x >> 3) + (blockIdx.x & 7) * 72;  // 576 = 8*72
    const int rb = tile / 12, cb = tile % 12;
    const int row0 = rb * 64, col0 = cb * 64;

    const unsigned short* X = Xb + (size_t)row0 * HH;
    const unsigned short* W; const float* wv;
    if (row0 < NROW1) { W = Wb;                    wv = wv1; }
    else              { W = Wb + (size_t)HH * HH;  wv = wv2; }

    const int l  = t & 63;
    const int w  = t >> 6;
    const int wr = w * 16;        // this wave's 16 output rows
    const int lc = l & 15;
    const int lk = (l >> 4) * 8;

    const unsigned short* ap = X + (size_t)(wr + lc) * HH + lk;         // A
    const unsigned short* bp = W + (size_t)(col0 + lc) * HH + lk;       // B n=0
    const size_t bn = (size_t)16 * HH;                                  // n stride

    f32x4 acc[4] = {};

    uint4 a0, b00, b01, b02, b03;
    uint4 a1, b10, b11, b12, b13;
    uint4 a2, b20, b21, b22, b23;

    auto LD = [&](uint4& A, uint4& B0, uint4& B1, uint4& B2, uint4& B3, int s) {
        const int ko = s * 32;
        A  = *(const uint4*)(ap + ko);
        B0 = *(const uint4*)(bp + ko);
        B1 = *(const uint4*)(bp + bn + ko);
        B2 = *(const uint4*)(bp + 2 * bn + ko);
        B3 = *(const uint4*)(bp + 3 * bn + ko);
    };
    auto MF = [&](uint4& A, uint4& B0, uint4& B1, uint4& B2, uint4& B3) {
        bf16x8 a = *reinterpret_cast<const bf16x8*>(&A);
        acc[0] = __builtin_amdgcn_mfma_f32_16x16x32_bf16(a, *(const bf16x8*)&B0, acc[0], 0, 0, 0);
        acc[1] = __builtin_amdgcn_mfma_f32_16x16x32_bf16(a, *(const bf16x8*)&B1, acc[1], 0, 0, 0);
        acc[2] = __builtin_amdgcn_mfma_f32_16x16x32_bf16(a, *(const bf16x8*)&B2, acc[2], 0, 0, 0);
        acc[3] = __builtin_amdgcn_mfma_f32_16x16x32_bf16(a, *(const bf16x8*)&B3, acc[3], 0, 0, 0);
    };

    LD(a0, b00, b01, b02, b03, 0);
    LD(a1, b10, b11, b12, b13, 1);

    #pragma unroll 1
    for (int s = 0; s < 24; s += 3) {            // 24 steps of k += 32
        LD(a2, b20, b21, b22, b23, s + 2);
        MF(a0, b00, b01, b02, b03);              // step s
        LD(a0, b00, b01, b02, b03, (s + 3 < 24) ? s + 3 : 23);
        MF(a1, b10, b11, b12, b13);              // step s+1
        LD(a1, b10, b11, b12, b13, (s + 4 < 24) ? s + 4 : 23);
        MF(a2, b20, b21, b22, b23);              // step s+2
    }

    // epilogue (verbatim r7): tanh * wvec over 64 cols, 16-lane reduce
    float wvn[4];
    #pragma unroll
    for (int n = 0; n < 4; ++n) wvn[n] = wv[col0 + n*16 + lc];
    #pragma unroll
    for (int i = 0; i < 4; ++i) {
        float s = 0.f;
        #pragma unroll
        for (int n = 0; n < 4; ++n) s += fast_tanh(acc[n][i]) * wvn[n];
        s += __shfl_xor(s, 1);
        s += __shfl_xor(s, 2);
        s += __shfl_xor(s, 4);
        s += __shfl_xor(s, 8);
        if (lc == 0)
            partial[(size_t)(row0 + wr + (l >> 4)*4 + i) * NCB + cb] = s;
    }
}

// ---------------------------------------------------------------------------
// Fused tail (verbatim r7): softmax from L2-hot partials + weighted sums +
// broadcast write. Grid (8, 48), 256 threads.
// ---------------------------------------------------------------------------
__global__ __launch_bounds__(256) void tail_kernel(
    const float* __restrict__ text, const float* __restrict__ dns,
    const float* __restrict__ partial, float* __restrict__ out)
{
    const int b = blockIdx.x, hc = blockIdx.y;   // hc 0..47
    const int t = threadIdx.x;
    __shared__ float p1s[128], p2s[256], red[8];
    __shared__ __align__(16) float bt[256], bd[256];

    if (t < 128) {
        const float* pr = partial + (size_t)(b * MM + t) * NCB;
        float s = 0.f;
        #pragma unroll
        for (int c = 0; c < NCB; ++c) s += pr[c];
        p1s[t] = s;
    }
    {
        const float* pr = partial + (size_t)(NROW1 + b * LL + t) * NCB;
        float s = 0.f;
        #pragma unroll
        for (int c = 0; c < NCB; ++c) s += pr[c];
        p2s[t] = s;
    }
    __syncthreads();

    float x1 = (t < 128) ? p1s[t] : -1e30f;
    float m1 = x1;
    #pragma unroll
    for (int d = 1; d < 64; d <<= 1) m1 = fmaxf(m1, __shfl_xor(m1, d));
    if ((t & 63) == 0) red[t >> 6] = m1;
    float x2 = p2s[t];
    float m2 = x2;
    #pragma unroll
    for (int d = 1; d < 64; d <<= 1) m2 = fmaxf(m2, __shfl_xor(m2, d));
    if ((t & 63) == 0) red[4 + (t >> 6)] = m2;
    __syncthreads();
    m1 = fmaxf(fmaxf(red[0], red[1]), fmaxf(red[2], red[3]));
    m2 = fmaxf(fmaxf(red[4], red[5]), fmaxf(red[6], red[7]));

    float e1 = (t < 128) ? __expf(x1 - m1) : 0.f;
    float e2 = __expf(x2 - m2);
    __syncthreads();
    float s1 = e1, s2 = e2;
    #pragma unroll
    for (int d = 1; d < 64; d <<= 1) { s1 += __shfl_xor(s1, d); s2 += __shfl_xor(s2, d); }
    if ((t & 63) == 0) { red[t >> 6] = s1; red[4 + (t >> 6)] = s2; }
    __syncthreads();
    s1 = red[0] + red[1] + red[2] + red[3];
    s2 = red[4] + red[5] + red[6] + red[7];
    if (t < 128) p1s[t] = e1 / s1;
    p2s[t] = e2 / s2;
    __syncthreads();

    const int hh  = hc * 16 + (t & 15);
    const int rsl = t >> 4;                      // 0..15 row-slices

    const int jr0 = rsl * 16;                    // 16 text rows per slice
    float st = 0.f;
    #pragma unroll
    for (int r = 0; r < 16; ++r)
        st = fmaf(p2s[jr0 + r], text[(size_t)(b * LL + jr0 + r) * HH + hh], st);

    const int mr0 = rsl * 8;                     // 8 dns rows per slice
    float sd = 0.f;
    #pragma unroll
    for (int r = 0; r < 8; ++r)
        sd = fmaf(p1s[mr0 + r], dns[(size_t)(b * MM + mr0 + r) * HH + hh], sd);

    bt[t] = st; bd[t] = sd;
    __syncthreads();
    if (t < 128) { bt[t] += bt[t + 128]; bd[t] += bd[t + 128]; } __syncthreads();
    if (t < 64)  { bt[t] += bt[t + 64];  bd[t] += bd[t + 64];  } __syncthreads();
    if (t < 32)  { bt[t] += bt[t + 32];  bd[t] += bd[t + 32];  } __syncthreads();
    if (t < 16)  { bt[t] += bt[t + 16];  bd[t] += bd[t + 16];  }
    __syncthreads();

    const int H4 = HH / 4;                       // 192
    const int n4out = NB * LL * H4;              // 393216
    const float4* svt4 = reinterpret_cast<const float4*>(bt);
    const float4* svd4 = reinterpret_cast<const float4*>(bd);
    float4* out4 = reinterpret_cast<float4*>(out);
    #pragma unroll
    for (int i = t; i < LL * 4; i += 256) {      // 1024 = 256 rows x 4 f4
        const int ll = i >> 2, c4 = i & 3;
        const size_t o = (size_t)(b * LL + ll) * H4 + hc * 4 + c4;
        out4[o] = svt4[c4];
        out4[n4out + o] = svd4[c4];
    }
}

extern "C" void kernel_launch(void* const* d_in, const int* in_sizes, int n_in,
                              void* d_out, int out_size, void* d_ws, size_t ws_size,
                              hipStream_t stream) {
    const float* text   = (const float*)d_in[0];   // (8,256,768)
    const float* dns    = (const float*)d_in[1];   // (8,128,768)
    const float* W_d1   = (const float*)d_in[4];   // (768,768)
    const float* w_att1 = (const float*)d_in[5];   // (1536,)
    const float* W_t2   = (const float*)d_in[9];   // (768,768)
    const float* w_att2 = (const float*)d_in[10];  // (1536,)

    float* ws      = (float*)d_ws;
    float* partial = ws;                                   // 36864 f
    unsigned short* Xb = (unsigned short*)(ws + 36864);    // 2359296 bf16
    unsigned short* Wb = Xb + (size_t)NROWS * HH;          // 1179648 bf16
    float* out     = (float*)d_out;

    prep_bf16<<<3456, 256, 0, stream>>>(
        (const float4*)text, (const float4*)dns, (const float4*)W_d1,
        (const float4*)W_t2, (uint2*)Xb, (uint2*)Wb);
    score_mfma<<<576, 256, 0, stream>>>(
        Xb, Wb, w_att1 + HH, w_att2 + HH, partial);
    tail_kernel<<<dim3(NB, 48), 256, 0, stream>>>(text, dns, partial, out);
}

// Round 13
// 29.630 us; speedup vs baseline: 2.0481x; 2.0481x over previous
//
#include <hip/hip_runtime.h>
#include <hip/hip_bf16.h>
#include <math.h>

#define HH 768
#define NB 8
#define LL 256
#define MM 128
#define NROW1 (NB*MM)        // 1024 dns rows
#define NROW2 (NB*LL)        // 2048 text rows
#define NROWS (NROW1+NROW2)  // 3072
#define NCB 12               // 768/64 column blocks

typedef __attribute__((ext_vector_type(8))) short  bf16x8;
typedef __attribute__((ext_vector_type(4))) float  f32x4;

static __device__ __forceinline__ unsigned int pkbf2(float a, float b) {
    __hip_bfloat162 h = __float22bfloat162_rn(make_float2(a, b));
    unsigned int u; __builtin_memcpy(&u, &h, 4); return u;
}

static __device__ __forceinline__ float fast_tanh(float x) {
    float e = __expf(2.0f * x);
    return 1.0f - 2.0f * __builtin_amdgcn_rcpf(e + 1.0f);
}

// async global->LDS DMA, 16B per lane. LDS dest = wave-uniform base + lane*16;
// global src is per-lane. Tracked by vmcnt; __syncthreads() drains it.
static __device__ __forceinline__ void gload_lds16(const void* g, void* l) {
    __builtin_amdgcn_global_load_lds(
        (const __attribute__((address_space(1))) unsigned int*)g,
        (__attribute__((address_space(3))) unsigned int*)l, 16, 0, 0);
}

// ---------------------------------------------------------------------------
// One-shot fp32 -> bf16 conversion of all GEMM operands. (verbatim r4-r7)
// ---------------------------------------------------------------------------
__global__ __launch_bounds__(256) void prep_bf16(
    const float4* __restrict__ text, const float4* __restrict__ dns,
    const float4* __restrict__ Wd1, const float4* __restrict__ Wt2,
    uint2* __restrict__ Xb, uint2* __restrict__ Wb)
{
    const int i = blockIdx.x * 256 + threadIdx.x;   // 884736 threads exactly
    const float4* src; uint2* dst;
    if (i < 589824) {
        dst = Xb + i;
        src = (i < 196608) ? (dns + i) : (text + (i - 196608));
    } else {
        dst = Wb + (i - 589824);
        src = (i < 737280) ? (Wd1 + (i - 589824)) : (Wt2 + (i - 737280));
    }
    float4 v = *src;
    uint2 o; o.x = pkbf2(v.x, v.y); o.y = pkbf2(v.z, v.w);
    *dst = o;
}

// ---------------------------------------------------------------------------
// Score GEMM v7: r7 block structure (576 blk x 4 waves, 64x64 tile, BK=64),
// staging switched to global_load_lds width=16 (async DMA, no VGPR round
// trip). LDS layout: [row][kchunk(8 bf16)] linear, 16B units -- lane i of a
// staging DMA = (row base + i>>3, chunk i&7) => LDS offset 16*i (linear ✓).
// Bank-conflict fix per rule #21: chunk c stored at c' = c ^ (row&7); the
// global SOURCE address applies the same XOR (values bit-identical, placement
// permuted), and the MFMA ds_read applies the XOR when fetching. Frag bits
// identical to r7 -> bit-identical acc. Double-buffered, 1 barrier/iter;
// next-tile DMA issued before the MFMA phase (hides L2 under MFMA+ds_read).
// ---------------------------------------------------------------------------
__global__ __launch_bounds__(256) void score_mfma(
    const unsigned short* __restrict__ Xb, const unsigned short* __restrict__ Wb,
    const float* __restrict__ wv1, const float* __restrict__ wv2,
    float* __restrict__ partial)
{
    __shared__ __align__(16) unsigned short A2[2][64 * 64];
    __shared__ __align__(16) unsigned short B2[2][64 * 64];

    const int t = threadIdx.x;
    const int tile = (blockIdx.x >> 3) + (blockIdx.x & 7) * 72;  // 576 = 8*72
    const int rb = tile / 12, cb = tile % 12;
    const int row0 = rb * 64, col0 = cb * 64;

    const unsigned short* X = Xb + (size_t)row0 * HH;
    const unsigned short* W; const float* wv;
    if (row0 < NROW1) { W = Wb;                    wv = wv1; }
    else              { W = Wb + (size_t)HH * HH;  wv = wv2; }

    const int l  = t & 63;
    const int w  = t >> 6;
    const int wr = w * 16;        // this wave's 16 output rows
    const int lc = l & 15;
    const int lk = (l >> 4) * 8;  // kept for doc; chunk idx used below

    // staging geometry: wave w stages tile-rows [w*16, w*16+16) as 2x 8-row
    // DMAs (A and B each). lane i: row off = i>>3, stored chunk = i&7,
    // global chunk = (i&7) ^ (i>>3)  [row&7 == i>>3 since parts are 8-aligned]
    const int roff = l >> 3;                    // 0..7
    const int gch  = ((l & 7) ^ roff) * 8;      // global k element offset
    const int rA0  = w * 16 + roff;             // A/B source row, part 0
    const unsigned short* apx = X + (size_t)rA0 * HH + gch;
    const unsigned short* bpx = W + (size_t)(col0 + rA0) * HH + gch;

    f32x4 acc[4] = {};

    auto STAGE = [&](int buf, int k0) {
        unsigned short* Abase = &A2[buf][(w * 16) * 64];
        unsigned short* Bbase = &B2[buf][(w * 16) * 64];
        gload_lds16(apx + k0,            Abase);            // A rows w*16..+8
        gload_lds16(apx + 8 * HH + k0,   Abase + 8 * 64);   // A rows +8..+16
        gload_lds16(bpx + k0,            Bbase);            // B rows
        gload_lds16(bpx + 8 * HH + k0,   Bbase + 8 * 64);
    };

    auto MFMA_TILE = [&](int buf) {
        #pragma unroll
        for (int kk = 0; kk < 2; ++kk) {
            const int C = kk * 4 + (l >> 4);                 // k-chunk 0..7
            const int sw = (C ^ (lc & 7)) * 8;               // swizzled chunk
            bf16x8 a = *reinterpret_cast<const bf16x8*>(&A2[buf][(wr + lc) * 64 + sw]);
            #pragma unroll
            for (int n = 0; n < 4; ++n) {
                bf16x8 b = *reinterpret_cast<const bf16x8*>(&B2[buf][(n * 16 + lc) * 64 + sw]);
                acc[n] = __builtin_amdgcn_mfma_f32_16x16x32_bf16(a, b, acc[n], 0, 0, 0);
            }
        }
    };

    STAGE(0, 0);
    __syncthreads();                 // drains vmcnt -> buf0 ready

    int buf = 0;
    #pragma unroll 1
    for (int k0 = 0; k0 < HH; k0 += 64) {
        if (k0 + 64 < HH) STAGE(buf ^ 1, k0 + 64);   // async, hides under MFMA
        MFMA_TILE(buf);
        __syncthreads();             // drains next-tile DMA + all LDS reads
        buf ^= 1;
    }

    // epilogue (verbatim r7): tanh * wvec over 64 cols, 16-lane reduce
    float wvn[4];
    #pragma unroll
    for (int n = 0; n < 4; ++n) wvn[n] = wv[col0 + n*16 + lc];
    #pragma unroll
    for (int i = 0; i < 4; ++i) {
        float s = 0.f;
        #pragma unroll
        for (int n = 0; n < 4; ++n) s += fast_tanh(acc[n][i]) * wvn[n];
        s += __shfl_xor(s, 1);
        s += __shfl_xor(s, 2);
        s += __shfl_xor(s, 4);
        s += __shfl_xor(s, 8);
        if (lc == 0)
            partial[(size_t)(row0 + wr + (l >> 4)*4 + i) * NCB + cb] = s;
    }
}

// ---------------------------------------------------------------------------
// Fused tail (verbatim r7): softmax from L2-hot partials + weighted sums +
// broadcast write. Grid (8, 48), 256 threads.
// ---------------------------------------------------------------------------
__global__ __launch_bounds__(256) void tail_kernel(
    const float* __restrict__ text, const float* __restrict__ dns,
    const float* __restrict__ partial, float* __restrict__ out)
{
    const int b = blockIdx.x, hc = blockIdx.y;   // hc 0..47
    const int t = threadIdx.x;
    __shared__ float p1s[128], p2s[256], red[8];
    __shared__ __align__(16) float bt[256], bd[256];

    if (t < 128) {
        const float* pr = partial + (size_t)(b * MM + t) * NCB;
        float s = 0.f;
        #pragma unroll
        for (int c = 0; c < NCB; ++c) s += pr[c];
        p1s[t] = s;
    }
    {
        const float* pr = partial + (size_t)(NROW1 + b * LL + t) * NCB;
        float s = 0.f;
        #pragma unroll
        for (int c = 0; c < NCB; ++c) s += pr[c];
        p2s[t] = s;
    }
    __syncthreads();

    float x1 = (t < 128) ? p1s[t] : -1e30f;
    float m1 = x1;
    #pragma unroll
    for (int d = 1; d < 64; d <<= 1) m1 = fmaxf(m1, __shfl_xor(m1, d));
    if ((t & 63) == 0) red[t >> 6] = m1;
    float x2 = p2s[t];
    float m2 = x2;
    #pragma unroll
    for (int d = 1; d < 64; d <<= 1) m2 = fmaxf(m2, __shfl_xor(m2, d));
    if ((t & 63) == 0) red[4 + (t >> 6)] = m2;
    __syncthreads();
    m1 = fmaxf(fmaxf(red[0], red[1]), fmaxf(red[2], red[3]));
    m2 = fmaxf(fmaxf(red[4], red[5]), fmaxf(red[6], red[7]));

    float e1 = (t < 128) ? __expf(x1 - m1) : 0.f;
    float e2 = __expf(x2 - m2);
    __syncthreads();
    float s1 = e1, s2 = e2;
    #pragma unroll
    for (int d = 1; d < 64; d <<= 1) { s1 += __shfl_xor(s1, d); s2 += __shfl_xor(s2, d); }
    if ((t & 63) == 0) { red[t >> 6] = s1; red[4 + (t >> 6)] = s2; }
    __syncthreads();
    s1 = red[0] + red[1] + red[2] + red[3];
    s2 = red[4] + red[5] + red[6] + red[7];
    if (t < 128) p1s[t] = e1 / s1;
    p2s[t] = e2 / s2;
    __syncthreads();

    const int hh  = hc * 16 + (t & 15);
    const int rsl = t >> 4;                      // 0..15 row-slices

    const int jr0 = rsl * 16;                    // 16 text rows per slice
    float st = 0.f;
    #pragma unroll
    for (int r = 0; r < 16; ++r)
        st = fmaf(p2s[jr0 + r], text[(size_t)(b * LL + jr0 + r) * HH + hh], st);

    const int mr0 = rsl * 8;                     // 8 dns rows per slice
    float sd = 0.f;
    #pragma unroll
    for (int r = 0; r < 8; ++r)
        sd = fmaf(p1s[mr0 + r], dns[(size_t)(b * MM + mr0 + r) * HH + hh], sd);

    bt[t] = st; bd[t] = sd;
    __syncthreads();
    if (t < 128) { bt[t] += bt[t + 128]; bd[t] += bd[t + 128]; } __syncthreads();
    if (t < 64)  { bt[t] += bt[t + 64];  bd[t] += bd[t + 64];  } __syncthreads();
    if (t < 32)  { bt[t] += bt[t + 32];  bd[t] += bd[t + 32];  } __syncthreads();
    if (t < 16)  { bt[t] += bt[t + 16];  bd[t] += bd[t + 16];  }
    __syncthreads();

    const int H4 = HH / 4;                       // 192
    const int n4out = NB * LL * H4;              // 393216
    const float4* svt4 = reinterpret_cast<const float4*>(bt);
    const float4* svd4 = reinterpret_cast<const float4*>(bd);
    float4* out4 = reinterpret_cast<float4*>(out);
    #pragma unroll
    for (int i = t; i < LL * 4; i += 256) {      // 1024 = 256 rows x 4 f4
        const int ll = i >> 2, c4 = i & 3;
        const size_t o = (size_t)(b * LL + ll) * H4 + hc * 4 + c4;
        out4[o] = svt4[c4];
        out4[n4out + o] = svd4[c4];
    }
}

extern "C" void kernel_launch(void* const* d_in, const int* in_sizes, int n_in,
                              void* d_out, int out_size, void* d_ws, size_t ws_size,
                              hipStream_t stream) {
    const float* text   = (const float*)d_in[0];   // (8,256,768)
    const float* dns    = (const float*)d_in[1];   // (8,128,768)
    const float* W_d1   = (const float*)d_in[4];   // (768,768)
    const float* w_att1 = (const float*)d_in[5];   // (1536,)
    const float* W_t2   = (const float*)d_in[9];   // (768,768)
    const float* w_att2 = (const float*)d_in[10];  // (1536,)

    float* ws      = (float*)d_ws;
    float* partial = ws;                                   // 36864 f
    unsigned short* Xb = (unsigned short*)(ws + 36864);    // 2359296 bf16
    unsigned short* Wb = Xb + (size_t)NROWS * HH;          // 1179648 bf16
    float* out     = (float*)d_out;

    prep_bf16<<<3456, 256, 0, stream>>>(
        (const float4*)text, (const float4*)dns, (const float4*)W_d1,
        (const float4*)W_t2, (uint2*)Xb, (uint2*)Wb);
    score_mfma<<<576, 256, 0, stream>>>(
        Xb, Wb, w_att1 + HH, w_att2 + HH, partial);
    tail_kernel<<<dim3(NB, 48), 256, 0, stream>>>(text, dns, partial, out);
}

// Round 14
// 28.292 us; speedup vs baseline: 2.1449x; 1.0473x over previous
//
#include <hip/hip_runtime.h>
#include <hip/hip_bf16.h>
#include <math.h>

#define HH 768
#define NB 8
#define LL 256
#define MM 128
#define NROW1 (NB*MM)        // 1024 dns rows
#define NROW2 (NB*LL)        // 2048 text rows
#define NROWS (NROW1+NROW2)  // 3072
#define NCB 12               // 768/64 column blocks

typedef __attribute__((ext_vector_type(8))) short  bf16x8;
typedef __attribute__((ext_vector_type(4))) float  f32x4;

static __device__ __forceinline__ unsigned int pkbf2(float a, float b) {
    __hip_bfloat162 h = __float22bfloat162_rn(make_float2(a, b));
    unsigned int u; __builtin_memcpy(&u, &h, 4); return u;
}

static __device__ __forceinline__ float fast_tanh(float x) {
    float e = __expf(2.0f * x);
    return 1.0f - 2.0f * __builtin_amdgcn_rcpf(e + 1.0f);
}

// async global->LDS DMA, 16B per lane (r13-proven).
static __device__ __forceinline__ void gload_lds16(const void* g, void* l) {
    __builtin_amdgcn_global_load_lds(
        (const __attribute__((address_space(1))) unsigned int*)g,
        (__attribute__((address_space(3))) unsigned int*)l, 16, 0, 0);
}

// ---------------------------------------------------------------------------
// One-shot fp32 -> bf16 conversion of all GEMM operands. (verbatim r4-r13)
// ---------------------------------------------------------------------------
__global__ __launch_bounds__(256) void prep_bf16(
    const float4* __restrict__ text, const float4* __restrict__ dns,
    const float4* __restrict__ Wd1, const float4* __restrict__ Wt2,
    uint2* __restrict__ Xb, uint2* __restrict__ Wb)
{
    const int i = blockIdx.x * 256 + threadIdx.x;   // 884736 threads exactly
    const float4* src; uint2* dst;
    if (i < 589824) {
        dst = Xb + i;
        src = (i < 196608) ? (dns + i) : (text + (i - 196608));
    } else {
        dst = Wb + (i - 589824);
        src = (i < 737280) ? (Wd1 + (i - 589824)) : (Wt2 + (i - 737280));
    }
    float4 v = *src;
    uint2 o; o.x = pkbf2(v.x, v.y); o.y = pkbf2(v.z, v.w);
    *dst = o;
}

// ---------------------------------------------------------------------------
// Score GEMM v8: r13's gload_lds16 + source-XOR-swizzle staging (proven),
// with the barrier-drain removed (T3/T4 mini): TRIPLE-buffered LDS, ONE raw
// s_barrier per iter, counted s_waitcnt vmcnt(4) -- tile k+1's 4 DMAs stay
// in flight across the barrier; only the last iter drains to 0.
// Safety: buf (k+2)%3 was last read at iter k-1; every ds_read feeds an MFMA
// before that iter's barrier (data-dep drains lgkmcnt), and all waves are
// past iter k's top barrier when STAGE issues. sched_barrier(0) pins the
// MFMA ds_reads before the STAGE DMAs. Numerics bit-identical to r13.
// ---------------------------------------------------------------------------
__global__ __launch_bounds__(256) void score_mfma(
    const unsigned short* __restrict__ Xb, const unsigned short* __restrict__ Wb,
    const float* __restrict__ wv1, const float* __restrict__ wv2,
    float* __restrict__ partial)
{
    __shared__ __align__(16) unsigned short A3[3][64 * 64];   // 24 KB
    __shared__ __align__(16) unsigned short B3[3][64 * 64];   // 24 KB

    const int t = threadIdx.x;
    const int tile = (blockIdx.x >> 3) + (blockIdx.x & 7) * 72;  // 576 = 8*72
    const int rb = tile / 12, cb = tile % 12;
    const int row0 = rb * 64, col0 = cb * 64;

    const unsigned short* X = Xb + (size_t)row0 * HH;
    const unsigned short* W; const float* wv;
    if (row0 < NROW1) { W = Wb;                    wv = wv1; }
    else              { W = Wb + (size_t)HH * HH;  wv = wv2; }

    const int l  = t & 63;
    const int w  = t >> 6;
    const int wr = w * 16;        // this wave's 16 output rows
    const int lc = l & 15;

    // staging geometry (verbatim r13): lane i stages row w*16 + (i>>3),
    // stored chunk i&7, global chunk (i&7)^(i>>3).
    const int roff = l >> 3;                    // 0..7
    const int gch  = ((l & 7) ^ roff) * 8;      // swizzled global k offset
    const int rA0  = w * 16 + roff;
    const unsigned short* apx = X + (size_t)rA0 * HH + gch;
    const unsigned short* bpx = W + (size_t)(col0 + rA0) * HH + gch;

    f32x4 acc[4] = {};

    auto STAGE = [&](int buf, int k0) {
        unsigned short* Abase = &A3[buf][(w * 16) * 64];
        unsigned short* Bbase = &B3[buf][(w * 16) * 64];
        gload_lds16(apx + k0,            Abase);
        gload_lds16(apx + 8 * HH + k0,   Abase + 8 * 64);
        gload_lds16(bpx + k0,            Bbase);
        gload_lds16(bpx + 8 * HH + k0,   Bbase + 8 * 64);
    };

    auto MFMA_TILE = [&](int buf) {
        #pragma unroll
        for (int kk = 0; kk < 2; ++kk) {
            const int C = kk * 4 + (l >> 4);                 // k-chunk 0..7
            const int sw = (C ^ (lc & 7)) * 8;               // swizzled chunk
            bf16x8 a = *reinterpret_cast<const bf16x8*>(&A3[buf][(wr + lc) * 64 + sw]);
            #pragma unroll
            for (int n = 0; n < 4; ++n) {
                bf16x8 b = *reinterpret_cast<const bf16x8*>(&B3[buf][(n * 16 + lc) * 64 + sw]);
                acc[n] = __builtin_amdgcn_mfma_f32_16x16x32_bf16(a, b, acc[n], 0, 0, 0);
            }
        }
    };

    // prologue: tiles 0,1 in flight (8 DMAs/wave outstanding)
    STAGE(0, 0);
    STAGE(1, 64);

    #pragma unroll 1
    for (int k = 0; k < 12; ++k) {
        if (k < 11) asm volatile("s_waitcnt vmcnt(4)" ::: "memory");
        else        asm volatile("s_waitcnt vmcnt(0)" ::: "memory");
        __builtin_amdgcn_s_barrier();         // tile k landed in all waves
        MFMA_TILE(k % 3);
        __builtin_amdgcn_sched_barrier(0);    // pin reads before next DMAs
        if (k < 10) STAGE((k + 2) % 3, (k + 2) * 64);
    }

    // epilogue (verbatim r7): tanh * wvec over 64 cols, 16-lane reduce
    float wvn[4];
    #pragma unroll
    for (int n = 0; n < 4; ++n) wvn[n] = wv[col0 + n*16 + lc];
    #pragma unroll
    for (int i = 0; i < 4; ++i) {
        float s = 0.f;
        #pragma unroll
        for (int n = 0; n < 4; ++n) s += fast_tanh(acc[n][i]) * wvn[n];
        s += __shfl_xor(s, 1);
        s += __shfl_xor(s, 2);
        s += __shfl_xor(s, 4);
        s += __shfl_xor(s, 8);
        if (lc == 0)
            partial[(size_t)(row0 + wr + (l >> 4)*4 + i) * NCB + cb] = s;
    }
}

// ---------------------------------------------------------------------------
// Fused tail (verbatim r7): softmax from L2-hot partials + weighted sums +
// broadcast write. Grid (8, 48), 256 threads.
// ---------------------------------------------------------------------------
__global__ __launch_bounds__(256) void tail_kernel(
    const float* __restrict__ text, const float* __restrict__ dns,
    const float* __restrict__ partial, float* __restrict__ out)
{
    const int b = blockIdx.x, hc = blockIdx.y;   // hc 0..47
    const int t = threadIdx.x;
    __shared__ float p1s[128], p2s[256], red[8];
    __shared__ __align__(16) float bt[256], bd[256];

    if (t < 128) {
        const float* pr = partial + (size_t)(b * MM + t) * NCB;
        float s = 0.f;
        #pragma unroll
        for (int c = 0; c < NCB; ++c) s += pr[c];
        p1s[t] = s;
    }
    {
        const float* pr = partial + (size_t)(NROW1 + b * LL + t) * NCB;
        float s = 0.f;
        #pragma unroll
        for (int c = 0; c < NCB; ++c) s += pr[c];
        p2s[t] = s;
    }
    __syncthreads();

    float x1 = (t < 128) ? p1s[t] : -1e30f;
    float m1 = x1;
    #pragma unroll
    for (int d = 1; d < 64; d <<= 1) m1 = fmaxf(m1, __shfl_xor(m1, d));
    if ((t & 63) == 0) red[t >> 6] = m1;
    float x2 = p2s[t];
    float m2 = x2;
    #pragma unroll
    for (int d = 1; d < 64; d <<= 1) m2 = fmaxf(m2, __shfl_xor(m2, d));
    if ((t & 63) == 0) red[4 + (t >> 6)] = m2;
    __syncthreads();
    m1 = fmaxf(fmaxf(red[0], red[1]), fmaxf(red[2], red[3]));
    m2 = fmaxf(fmaxf(red[4], red[5]), fmaxf(red[6], red[7]));

    float e1 = (t < 128) ? __expf(x1 - m1) : 0.f;
    float e2 = __expf(x2 - m2);
    __syncthreads();
    float s1 = e1, s2 = e2;
    #pragma unroll
    for (int d = 1; d < 64; d <<= 1) { s1 += __shfl_xor(s1, d); s2 += __shfl_xor(s2, d); }
    if ((t & 63) == 0) { red[t >> 6] = s1; red[4 + (t >> 6)] = s2; }
    __syncthreads();
    s1 = red[0] + red[1] + red[2] + red[3];
    s2 = red[4] + red[5] + red[6] + red[7];
    if (t < 128) p1s[t] = e1 / s1;
    p2s[t] = e2 / s2;
    __syncthreads();

    const int hh  = hc * 16 + (t & 15);
    const int rsl = t >> 4;                      // 0..15 row-slices

    const int jr0 = rsl * 16;                    // 16 text rows per slice
    float st = 0.f;
    #pragma unroll
    for (int r = 0; r < 16; ++r)
        st = fmaf(p2s[jr0 + r], text[(size_t)(b * LL + jr0 + r) * HH + hh], st);

    const int mr0 = rsl * 8;                     // 8 dns rows per slice
    float sd = 0.f;
    #pragma unroll
    for (int r = 0; r < 8; ++r)
        sd = fmaf(p1s[mr0 + r], dns[(size_t)(b * MM + mr0 + r) * HH + hh], sd);

    bt[t] = st; bd[t] = sd;
    __syncthreads();
    if (t < 128) { bt[t] += bt[t + 128]; bd[t] += bd[t + 128]; } __syncthreads();
    if (t < 64)  { bt[t] += bt[t + 64];  bd[t] += bd[t + 64];  } __syncthreads();
    if (t < 32)  { bt[t] += bt[t + 32];  bd[t] += bd[t + 32];  } __syncthreads();
    if (t < 16)  { bt[t] += bt[t + 16];  bd[t] += bd[t + 16];  }
    __syncthreads();

    const int H4 = HH / 4;                       // 192
    const int n4out = NB * LL * H4;              // 393216
    const float4* svt4 = reinterpret_cast<const float4*>(bt);
    const float4* svd4 = reinterpret_cast<const float4*>(bd);
    float4* out4 = reinterpret_cast<float4*>(out);
    #pragma unroll
    for (int i = t; i < LL * 4; i += 256) {      // 1024 = 256 rows x 4 f4
        const int ll = i >> 2, c4 = i & 3;
        const size_t o = (size_t)(b * LL + ll) * H4 + hc * 4 + c4;
        out4[o] = svt4[c4];
        out4[n4out + o] = svd4[c4];
    }
}

extern "C" void kernel_launch(void* const* d_in, const int* in_sizes, int n_in,
                              void* d_out, int out_size, void* d_ws, size_t ws_size,
                              hipStream_t stream) {
    const float* text   = (const float*)d_in[0];   // (8,256,768)
    const float* dns    = (const float*)d_in[1];   // (8,128,768)
    const float* W_d1   = (const float*)d_in[4];   // (768,768)
    const float* w_att1 = (const float*)d_in[5];   // (1536,)
    const float* W_t2   = (const float*)d_in[9];   // (768,768)
    const float* w_att2 = (const float*)d_in[10];  // (1536,)

    float* ws      = (float*)d_ws;
    float* partial = ws;                                   // 36864 f
    unsigned short* Xb = (unsigned short*)(ws + 36864);    // 2359296 bf16
    unsigned short* Wb = Xb + (size_t)NROWS * HH;          // 1179648 bf16
    float* out     = (float*)d_out;

    prep_bf16<<<3456, 256, 0, stream>>>(
        (const float4*)text, (const float4*)dns, (const float4*)W_d1,
        (const float4*)W_t2, (uint2*)Xb, (uint2*)Wb);
    score_mfma<<<576, 256, 0, stream>>>(
        Xb, Wb, w_att1 + HH, w_att2 + HH, partial);
    tail_kernel<<<dim3(NB, 48), 256, 0, stream>>>(text, dns, partial, out);
}